// Round 1
// baseline (1559.601 us; speedup 1.0000x reference)
//
#include <hip/hip_runtime.h>

#define NN 50000
#define NE 1000000

constexpr float LN_EPS = 1e-5f;

// ---------------------------------------------------------------------------
// Layer 0 message: msg = relu(x[src] + ea @ lw + lb), D=16. One thread per (e,d).
__global__ __launch_bounds__(256) void msg0_kernel(
    const float* __restrict__ x, const int* __restrict__ ei,
    const float* __restrict__ ea, const float* __restrict__ lw,
    const float* __restrict__ lb, float* __restrict__ aggr) {
  int t = blockIdx.x * 256 + threadIdx.x;       // exact grid: NE*16 threads
  int e = t >> 4, d = t & 15;
  int src = ei[e], dst = ei[NE + e];
  float m = lb[d] + x[src * 16 + d];
#pragma unroll
  for (int i = 0; i < 8; i++) m = fmaf(ea[e * 8 + i], lw[i * 16 + d], m);
  m = fmaxf(m, 0.f);
  unsafeAtomicAdd(&aggr[dst * 16 + d], m);
}

// ---------------------------------------------------------------------------
// Layers 1/2 message: D=64. One wave per edge, lane = channel.
__global__ __launch_bounds__(256) void msg_kernel(
    const float* __restrict__ h, const int* __restrict__ ei,
    const float* __restrict__ ea, const float* __restrict__ lw,
    const float* __restrict__ lb, float* __restrict__ aggr) {
  int e = blockIdx.x * 4 + (threadIdx.x >> 6);  // exact grid: NE waves
  int d = threadIdx.x & 63;
  int src = ei[e], dst = ei[NE + e];
  float m = lb[d] + h[src * 64 + d];
#pragma unroll
  for (int i = 0; i < 8; i++) m = fmaf(ea[e * 8 + i], lw[i * 64 + d], m);
  m = fmaxf(m, 0.f);
  unsafeAtomicAdd(&aggr[dst * 64 + d], m);
}

// ---------------------------------------------------------------------------
// LayerNorm across the 64 lanes of a wave (population variance, ddof=0).
__device__ inline float lane_layernorm(float r, float g, float b) {
  float s = r;
#pragma unroll
  for (int m = 32; m >= 1; m >>= 1) s += __shfl_xor(s, m);
  float mu = s * (1.f / 64.f);
  float dv = r - mu;
  float v = dv * dv;
#pragma unroll
  for (int m = 32; m >= 1; m >>= 1) v += __shfl_xor(v, m);
  float var = v * (1.f / 64.f);
  return dv * rsqrtf(var + LN_EPS) * g + b;
}

// ---------------------------------------------------------------------------
// Layer 0 node update: h = LN(relu(relu((x+aggr)@w1+b1)@w2+b2) + x@rw+rb)
// One wave per node, lane j = output channel.
__global__ __launch_bounds__(256) void node0_kernel(
    const float* __restrict__ x, const float* __restrict__ aggr,
    const float* __restrict__ w1, const float* __restrict__ b1,
    const float* __restrict__ w2, const float* __restrict__ b2,
    const float* __restrict__ lng, const float* __restrict__ lnb,
    const float* __restrict__ rw, const float* __restrict__ rb,
    float* __restrict__ h) {
  int n = blockIdx.x * 4 + (threadIdx.x >> 6);  // exact grid: NN waves
  int j = threadIdx.x & 63;
  float xv[16], tv[16];
#pragma unroll
  for (int k = 0; k < 16; k++) {
    xv[k] = x[n * 16 + k];
    tv[k] = xv[k] + aggr[n * 16 + k];
  }
  float q = b1[j];
#pragma unroll
  for (int k = 0; k < 16; k++) q = fmaf(tv[k], w1[k * 64 + j], q);
  q = fmaxf(q, 0.f);
  float h2 = b2[j];
  for (int k = 0; k < 64; k++) h2 = fmaf(__shfl(q, k), w2[k * 64 + j], h2);
  h2 = fmaxf(h2, 0.f);
  float res = rb[j];
#pragma unroll
  for (int k = 0; k < 16; k++) res = fmaf(xv[k], rw[k * 64 + j], res);
  h[n * 64 + j] = lane_layernorm(h2 + res, lng[j], lnb[j]);
}

// ---------------------------------------------------------------------------
// Layers 1/2 node update: residual = identity; in-place on h.
__global__ __launch_bounds__(256) void node_kernel(
    float* __restrict__ h, const float* __restrict__ aggr,
    const float* __restrict__ w1, const float* __restrict__ b1,
    const float* __restrict__ w2, const float* __restrict__ b2,
    const float* __restrict__ lng, const float* __restrict__ lnb) {
  int n = blockIdx.x * 4 + (threadIdx.x >> 6);
  int j = threadIdx.x & 63;
  float hin = h[n * 64 + j];
  float t = hin + aggr[n * 64 + j];
  float q = b1[j];
  for (int k = 0; k < 64; k++) q = fmaf(__shfl(t, k), w1[k * 64 + j], q);
  q = fmaxf(q, 0.f);
  float h2 = b2[j];
  for (int k = 0; k < 64; k++) h2 = fmaf(__shfl(q, k), w2[k * 64 + j], h2);
  h2 = fmaxf(h2, 0.f);
  h[n * 64 + j] = lane_layernorm(h2 + hin, lng[j], lnb[j]);
}

// ---------------------------------------------------------------------------
// Decoder: per edge z = [hs, hd, |hs-hd|, hs*hd, ea] (264) -> 64 -> 32 -> 1.
// One wave per 8 edges; Z stored transposed in LDS; lane j = y1 channel.
__global__ __launch_bounds__(256) void decoder_kernel(
    const float* __restrict__ h, const int* __restrict__ ei,
    const float* __restrict__ ea, const float* __restrict__ w1,
    const float* __restrict__ b1, const float* __restrict__ w2,
    const float* __restrict__ b2, const float* __restrict__ w3,
    const float* __restrict__ b3, float* __restrict__ out) {
  __shared__ float zT[4][264 * 8];   // [wave][k*8+e]
  __shared__ float y1s[4][8 * 64];   // [wave][e*64+j]
  int w = threadIdx.x >> 6;
  int j = threadIdx.x & 63;
  int g = blockIdx.x * 4 + w;        // exact grid: NE/8 waves
  int e0 = g * 8;
  float* z = zT[w];

  int s[8], d[8];
#pragma unroll
  for (int e = 0; e < 8; e++) {
    s[e] = ei[e0 + e];
    d[e] = ei[NE + e0 + e];
  }
  float hs[8], hd[8];
#pragma unroll
  for (int e = 0; e < 8; e++) {
    hs[e] = h[s[e] * 64 + j];
    hd[e] = h[d[e] * 64 + j];
  }
  // stage Z^T: rows k=j (hs), 64+j (hd), 128+j (abs), 192+j (prod)
  *(float4*)&z[j * 8 + 0] = make_float4(hs[0], hs[1], hs[2], hs[3]);
  *(float4*)&z[j * 8 + 4] = make_float4(hs[4], hs[5], hs[6], hs[7]);
  *(float4*)&z[(64 + j) * 8 + 0] = make_float4(hd[0], hd[1], hd[2], hd[3]);
  *(float4*)&z[(64 + j) * 8 + 4] = make_float4(hd[4], hd[5], hd[6], hd[7]);
  *(float4*)&z[(128 + j) * 8 + 0] =
      make_float4(fabsf(hs[0] - hd[0]), fabsf(hs[1] - hd[1]),
                  fabsf(hs[2] - hd[2]), fabsf(hs[3] - hd[3]));
  *(float4*)&z[(128 + j) * 8 + 4] =
      make_float4(fabsf(hs[4] - hd[4]), fabsf(hs[5] - hd[5]),
                  fabsf(hs[6] - hd[6]), fabsf(hs[7] - hd[7]));
  *(float4*)&z[(192 + j) * 8 + 0] =
      make_float4(hs[0] * hd[0], hs[1] * hd[1], hs[2] * hd[2], hs[3] * hd[3]);
  *(float4*)&z[(192 + j) * 8 + 4] =
      make_float4(hs[4] * hd[4], hs[5] * hd[5], hs[6] * hd[6], hs[7] * hd[7]);
  {
    // edge attrs: lane j -> edge e=j>>3, feat i=j&7 (coalesced read)
    float v = ea[e0 * 8 + j];
    z[(256 + (j & 7)) * 8 + (j >> 3)] = v;
  }
  // same-wave LDS write->read; HW processes DS ops of a wave in order.

  float acc[8];
#pragma unroll
  for (int e = 0; e < 8; e++) acc[e] = 0.f;
  for (int k = 0; k < 264; k++) {
    float wv = w1[k * 64 + j];
    float4 za = *(float4*)&z[k * 8 + 0];
    float4 zb = *(float4*)&z[k * 8 + 4];
    acc[0] = fmaf(za.x, wv, acc[0]);
    acc[1] = fmaf(za.y, wv, acc[1]);
    acc[2] = fmaf(za.z, wv, acc[2]);
    acc[3] = fmaf(za.w, wv, acc[3]);
    acc[4] = fmaf(zb.x, wv, acc[4]);
    acc[5] = fmaf(zb.y, wv, acc[5]);
    acc[6] = fmaf(zb.z, wv, acc[6]);
    acc[7] = fmaf(zb.w, wv, acc[7]);
  }
  float bj = b1[j];
#pragma unroll
  for (int e = 0; e < 8; e++) y1s[w][e * 64 + j] = fmaxf(acc[e] + bj, 0.f);

  // layers 2+3: lanes 0..31 handle even-ish e, 32..63 the others
  int half = j >> 5, i = j & 31;
  float w3v = w3[i];
  float b3v = b3[0];
#pragma unroll
  for (int p = 0; p < 4; p++) {
    int e = half + 2 * p;
    float y2 = b2[i];
    for (int k = 0; k < 64; k++) y2 = fmaf(y1s[w][e * 64 + k], w2[k * 32 + i], y2);
    y2 = fmaxf(y2, 0.f);
    float part = y2 * w3v;
#pragma unroll
    for (int mm = 16; mm >= 1; mm >>= 1) part += __shfl_xor(part, mm);
    if (i == 0) out[e0 + e] = part + b3v;
  }
}

// ---------------------------------------------------------------------------
extern "C" void kernel_launch(void* const* d_in, const int* in_sizes, int n_in,
                              void* d_out, int out_size, void* d_ws, size_t ws_size,
                              hipStream_t stream) {
  const float* x = (const float*)d_in[0];
  const int* ei = (const int*)d_in[1];
  const float* ea = (const float*)d_in[2];
  const float* l0_lin_w = (const float*)d_in[3];
  const float* l0_lin_b = (const float*)d_in[4];
  const float* l0_w1 = (const float*)d_in[5];
  const float* l0_b1 = (const float*)d_in[6];
  const float* l0_w2 = (const float*)d_in[7];
  const float* l0_b2 = (const float*)d_in[8];
  const float* l0_ln_g = (const float*)d_in[9];
  const float* l0_ln_b = (const float*)d_in[10];
  const float* l0_res_w = (const float*)d_in[11];
  const float* l0_res_b = (const float*)d_in[12];
  const float* dec_w1 = (const float*)d_in[29];
  const float* dec_b1 = (const float*)d_in[30];
  const float* dec_w2 = (const float*)d_in[31];
  const float* dec_b2 = (const float*)d_in[32];
  const float* dec_w3 = (const float*)d_in[33];
  const float* dec_b3 = (const float*)d_in[34];

  float* h = (float*)d_ws;                       // NN*64 floats
  float* aggr = h + (size_t)NN * 64;             // NN*64 floats

  // ---- layer 0 ----
  hipMemsetAsync(aggr, 0, (size_t)NN * 16 * sizeof(float), stream);
  msg0_kernel<<<(NE * 16) / 256, 256, 0, stream>>>(x, ei, ea, l0_lin_w, l0_lin_b, aggr);
  node0_kernel<<<NN / 4, 256, 0, stream>>>(x, aggr, l0_w1, l0_b1, l0_w2, l0_b2,
                                           l0_ln_g, l0_ln_b, l0_res_w, l0_res_b, h);
  // ---- layers 1, 2 ----
  for (int li = 1; li <= 2; li++) {
    int base = 13 + (li - 1) * 8;
    const float* lin_w = (const float*)d_in[base + 0];
    const float* lin_b = (const float*)d_in[base + 1];
    const float* w1 = (const float*)d_in[base + 2];
    const float* b1 = (const float*)d_in[base + 3];
    const float* w2 = (const float*)d_in[base + 4];
    const float* b2 = (const float*)d_in[base + 5];
    const float* lng = (const float*)d_in[base + 6];
    const float* lnb = (const float*)d_in[base + 7];
    hipMemsetAsync(aggr, 0, (size_t)NN * 64 * sizeof(float), stream);
    msg_kernel<<<NE / 4, 256, 0, stream>>>(h, ei, ea, lin_w, lin_b, aggr);
    node_kernel<<<NN / 4, 256, 0, stream>>>(h, aggr, w1, b1, w2, b2, lng, lnb);
  }
  // ---- decoder ----
  decoder_kernel<<<NE / 8 / 4, 256, 0, stream>>>(h, ei, ea, dec_w1, dec_b1, dec_w2,
                                                 dec_b2, dec_w3, dec_b3, (float*)d_out);
}

// Round 2
// 1050.515 us; speedup vs baseline: 1.4846x; 1.4846x over previous
//
#include <hip/hip_runtime.h>

#define NN 50000
#define NE 1000000

constexpr float LN_EPS = 1e-5f;

typedef short bf16x8 __attribute__((ext_vector_type(8)));
typedef float f32x4 __attribute__((ext_vector_type(4)));

// round-to-nearest-even float -> bf16
__device__ inline ushort f2bf(float x) {
  union { float f; uint u; } v; v.f = x;
  uint r = v.u + 0x7fffu + ((v.u >> 16) & 1u);
  return (ushort)(r >> 16);
}
__device__ inline uint pkbf(float a, float b) {
  union { float f; uint u; } x, y; x.f = a; y.f = b;
  uint ra = (x.u + 0x7fffu + ((x.u >> 16) & 1u)) >> 16;
  uint rb = (y.u + 0x7fffu + ((y.u >> 16) & 1u)) & 0xffff0000u;
  return ra | rb;
}

// ---------------------------------------------------------------------------
// Layer 0 message: msg = relu(x[src] + ea @ lw + lb), D=16. One thread per (e,d).
__global__ __launch_bounds__(256) void msg0_kernel(
    const float* __restrict__ x, const int* __restrict__ ei,
    const float* __restrict__ ea, const float* __restrict__ lw,
    const float* __restrict__ lb, float* __restrict__ aggr) {
  int t = blockIdx.x * 256 + threadIdx.x;
  int e = t >> 4, d = t & 15;
  int src = ei[e], dst = ei[NE + e];
  float m = lb[d] + x[src * 16 + d];
#pragma unroll
  for (int i = 0; i < 8; i++) m = fmaf(ea[e * 8 + i], lw[i * 16 + d], m);
  m = fmaxf(m, 0.f);
  unsafeAtomicAdd(&aggr[dst * 16 + d], m);
}

// ---------------------------------------------------------------------------
// Layers 1/2 message: D=64. One wave per edge, lane = channel.
__global__ __launch_bounds__(256) void msg_kernel(
    const float* __restrict__ h, const int* __restrict__ ei,
    const float* __restrict__ ea, const float* __restrict__ lw,
    const float* __restrict__ lb, float* __restrict__ aggr) {
  int e = blockIdx.x * 4 + (threadIdx.x >> 6);
  int d = threadIdx.x & 63;
  int src = ei[e], dst = ei[NE + e];
  float m = lb[d] + h[src * 64 + d];
#pragma unroll
  for (int i = 0; i < 8; i++) m = fmaf(ea[e * 8 + i], lw[i * 64 + d], m);
  m = fmaxf(m, 0.f);
  unsafeAtomicAdd(&aggr[dst * 64 + d], m);
}

// ---------------------------------------------------------------------------
__device__ inline float lane_layernorm(float r, float g, float b) {
  float s = r;
#pragma unroll
  for (int m = 32; m >= 1; m >>= 1) s += __shfl_xor(s, m);
  float mu = s * (1.f / 64.f);
  float dv = r - mu;
  float v = dv * dv;
#pragma unroll
  for (int m = 32; m >= 1; m >>= 1) v += __shfl_xor(v, m);
  float var = v * (1.f / 64.f);
  return dv * rsqrtf(var + LN_EPS) * g + b;
}

// ---------------------------------------------------------------------------
__global__ __launch_bounds__(256) void node0_kernel(
    const float* __restrict__ x, const float* __restrict__ aggr,
    const float* __restrict__ w1, const float* __restrict__ b1,
    const float* __restrict__ w2, const float* __restrict__ b2,
    const float* __restrict__ lng, const float* __restrict__ lnb,
    const float* __restrict__ rw, const float* __restrict__ rb,
    float* __restrict__ h) {
  int n = blockIdx.x * 4 + (threadIdx.x >> 6);
  int j = threadIdx.x & 63;
  float xv[16], tv[16];
#pragma unroll
  for (int k = 0; k < 16; k++) {
    xv[k] = x[n * 16 + k];
    tv[k] = xv[k] + aggr[n * 16 + k];
  }
  float q = b1[j];
#pragma unroll
  for (int k = 0; k < 16; k++) q = fmaf(tv[k], w1[k * 64 + j], q);
  q = fmaxf(q, 0.f);
  float h2 = b2[j];
  for (int k = 0; k < 64; k++) h2 = fmaf(__shfl(q, k), w2[k * 64 + j], h2);
  h2 = fmaxf(h2, 0.f);
  float res = rb[j];
#pragma unroll
  for (int k = 0; k < 16; k++) res = fmaf(xv[k], rw[k * 64 + j], res);
  h[n * 64 + j] = lane_layernorm(h2 + res, lng[j], lnb[j]);
}

// ---------------------------------------------------------------------------
__global__ __launch_bounds__(256) void node_kernel(
    float* __restrict__ h, const float* __restrict__ aggr,
    const float* __restrict__ w1, const float* __restrict__ b1,
    const float* __restrict__ w2, const float* __restrict__ b2,
    const float* __restrict__ lng, const float* __restrict__ lnb) {
  int n = blockIdx.x * 4 + (threadIdx.x >> 6);
  int j = threadIdx.x & 63;
  float hin = h[n * 64 + j];
  float t = hin + aggr[n * 64 + j];
  float q = b1[j];
  for (int k = 0; k < 64; k++) q = fmaf(__shfl(t, k), w1[k * 64 + j], q);
  q = fmaxf(q, 0.f);
  float h2 = b2[j];
  for (int k = 0; k < 64; k++) h2 = fmaf(__shfl(q, k), w2[k * 64 + j], h2);
  h2 = fmaxf(h2, 0.f);
  h[n * 64 + j] = lane_layernorm(h2 + hin, lng[j], lnb[j]);
}

// ---------------------------------------------------------------------------
// Prep: arrange dec_w1 (264x64, K zero-padded to 288) and dec_w2 (64x32) into
// per-lane bf16 B-fragments for mfma_f32_16x16x32_bf16.
// w1f: frag f = kstep*4+ntile (f<36): elem (f*64+lane)*8+j = w1[k][n] where
//   k = (f>>2)*32 + (lane>>4)*8 + j, n = (f&3)*16 + (lane&15)
// w2f: frag f = kstep*2+ntile (f<4): k = (f>>1)*32+(lane>>4)*8+j, n=(f&1)*16+(lane&15)
__global__ __launch_bounds__(256) void prep_kernel(
    const float* __restrict__ w1, const float* __restrict__ w2,
    ushort* __restrict__ w1f, ushort* __restrict__ w2f) {
  int t = blockIdx.x * 256 + threadIdx.x;   // grid: 80*256 = 20480 = 18432+2048
  if (t < 18432) {
    int j = t & 7, lane = (t >> 3) & 63, f = t >> 9;
    int k = (f >> 2) * 32 + ((lane >> 4) * 8) + j;
    int n = (f & 3) * 16 + (lane & 15);
    float v = (k < 264) ? w1[k * 64 + n] : 0.f;
    w1f[t] = f2bf(v);
  } else {
    int t2 = t - 18432;
    int j = t2 & 7, lane = (t2 >> 3) & 63, f = t2 >> 9;
    int k = (f >> 1) * 32 + ((lane >> 4) * 8) + j;
    int n = (f & 1) * 16 + (lane & 15);
    w2f[t2] = f2bf(w2[k * 32 + n]);
  }
}

// ---------------------------------------------------------------------------
// MFMA decoder: wave-per-16-edges. Z (16x288 bf16, LDS stride 296) built from
// h gathers; GEMM1 = 9 ksteps x 4 ntiles of 16x16x32 bf16 MFMA; Y1 relu->bf16
// LDS round-trip; GEMM2 = 2x2 MFMAs; W3 via shuffle reduce.
#define GPW 5   // groups per wave: 3125 blocks * 4 waves * 5 = 62500 groups
#define ZS 296  // Z row stride (bf16): 2-way (free) LDS bank pattern, 16B-aligned rows
#define YS 72

__global__ __launch_bounds__(256) void decoder_kernel(
    const float* __restrict__ h, const int* __restrict__ ei,
    const float* __restrict__ ea,
    const ushort* __restrict__ w1f, const ushort* __restrict__ w2f,
    const float* __restrict__ b1, const float* __restrict__ b2,
    const float* __restrict__ w3, const float* __restrict__ b3,
    float* __restrict__ out) {
  __shared__ ushort zbuf[4][16 * ZS];
  __shared__ ushort y1buf[4][16 * YS];
  const int w = threadIdx.x >> 6, l = threadIdx.x & 63;
  const int sub = l & 15, quad = l >> 4;
  ushort* Z = zbuf[w];
  ushort* Y = y1buf[w];

  // zero K-pad cols 264..287 once (never rewritten by staging)
#pragma unroll
  for (int t = 0; t < 3; t++) {
    int idx = l * 3 + t;              // 0..191
    int m = idx / 12, cp = idx % 12;
    *(uint*)&Z[m * ZS + 264 + cp * 2] = 0;
  }
  // hoisted per-lane constants
  float b1v[4];
#pragma unroll
  for (int t = 0; t < 4; t++) b1v[t] = b1[t * 16 + sub];
  float b2v0 = b2[sub], b2v1 = b2[16 + sub];
  float w3v0 = w3[sub], w3v1 = w3[16 + sub];
  float b3v = b3[0];
  bf16x8 w2frag[4];
#pragma unroll
  for (int f = 0; f < 4; f++) w2frag[f] = ((const bf16x8*)w2f)[f * 64 + l];

  const int gbase = (blockIdx.x * 4 + w) * GPW;
  for (int it = 0; it < GPW; it++) {
    const int g = gbase + it;
    const int e0 = g * 16;
    int sl = ei[e0 + sub];
    int dl = ei[NE + e0 + sub];

    // ---- stage Z ----
#pragma unroll
    for (int i = 0; i < 4; i++) {
      int e = 4 * i + quad;
      int s = __shfl(sl, e), d = __shfl(dl, e);
      float4 a = ((const float4*)h)[s * 16 + sub];
      float4 b = ((const float4*)h)[d * 16 + sub];
      uint2 u;
      u.x = pkbf(a.x, a.y); u.y = pkbf(a.z, a.w);
      *(uint2*)&Z[e * ZS + sub * 4] = u;
      u.x = pkbf(b.x, b.y); u.y = pkbf(b.z, b.w);
      *(uint2*)&Z[e * ZS + 64 + sub * 4] = u;
      u.x = pkbf(fabsf(a.x - b.x), fabsf(a.y - b.y));
      u.y = pkbf(fabsf(a.z - b.z), fabsf(a.w - b.w));
      *(uint2*)&Z[e * ZS + 128 + sub * 4] = u;
      u.x = pkbf(a.x * b.x, a.y * b.y);
      u.y = pkbf(a.z * b.z, a.w * b.w);
      *(uint2*)&Z[e * ZS + 192 + sub * 4] = u;
    }
    {
      float2 eav = ((const float2*)ea)[e0 * 4 + l];   // edge l>>2, cols 2*(l&3)
      *(uint*)&Z[(l >> 2) * ZS + 256 + 2 * (l & 3)] = pkbf(eav.x, eav.y);
    }
    // same-wave DS ordering: staging writes precede frag reads in program order

    // ---- GEMM1: Z(16x288) @ W1(288x64) ----
    f32x4 acc[4];
#pragma unroll
    for (int t = 0; t < 4; t++) acc[t] = (f32x4){0.f, 0.f, 0.f, 0.f};
    for (int s = 0; s < 9; s++) {
      bf16x8 af = *(const bf16x8*)&Z[sub * ZS + s * 32 + quad * 8];
#pragma unroll
      for (int t = 0; t < 4; t++)
        acc[t] = __builtin_amdgcn_mfma_f32_16x16x32_bf16(
            af, ((const bf16x8*)w1f)[(s * 4 + t) * 64 + l], acc[t], 0, 0, 0);
    }
    // ---- relu + bf16 -> Y1 (C layout: row = quad*4+r, col = t*16+sub) ----
#pragma unroll
    for (int t = 0; t < 4; t++)
#pragma unroll
      for (int r = 0; r < 4; r++)
        Y[(quad * 4 + r) * YS + t * 16 + sub] = f2bf(fmaxf(acc[t][r] + b1v[t], 0.f));

    // ---- GEMM2: Y1(16x64) @ W2(64x32) ----
    f32x4 acc2[2];
    acc2[0] = (f32x4){0.f, 0.f, 0.f, 0.f};
    acc2[1] = (f32x4){0.f, 0.f, 0.f, 0.f};
#pragma unroll
    for (int ks = 0; ks < 2; ks++) {
      union { bf16x8 v; ushort4 u[2]; } ya;
      int off = sub * YS + ks * 32 + quad * 8;
      ya.u[0] = *(const ushort4*)&Y[off];
      ya.u[1] = *(const ushort4*)&Y[off + 4];
      acc2[0] = __builtin_amdgcn_mfma_f32_16x16x32_bf16(ya.v, w2frag[ks * 2 + 0], acc2[0], 0, 0, 0);
      acc2[1] = __builtin_amdgcn_mfma_f32_16x16x32_bf16(ya.v, w2frag[ks * 2 + 1], acc2[1], 0, 0, 0);
    }
    // ---- relu, W3 dot, reduce across 16 cols (lanes of same quad) ----
#pragma unroll
    for (int r = 0; r < 4; r++) {
      float o = fmaxf(acc2[0][r] + b2v0, 0.f) * w3v0 +
                fmaxf(acc2[1][r] + b2v1, 0.f) * w3v1;
      o += __shfl_xor(o, 1);
      o += __shfl_xor(o, 2);
      o += __shfl_xor(o, 4);
      o += __shfl_xor(o, 8);
      if (sub == 0) out[e0 + quad * 4 + r] = o + b3v;
    }
  }
}

// ---------------------------------------------------------------------------
extern "C" void kernel_launch(void* const* d_in, const int* in_sizes, int n_in,
                              void* d_out, int out_size, void* d_ws, size_t ws_size,
                              hipStream_t stream) {
  const float* x = (const float*)d_in[0];
  const int* ei = (const int*)d_in[1];
  const float* ea = (const float*)d_in[2];
  const float* l0_lin_w = (const float*)d_in[3];
  const float* l0_lin_b = (const float*)d_in[4];
  const float* l0_w1 = (const float*)d_in[5];
  const float* l0_b1 = (const float*)d_in[6];
  const float* l0_w2 = (const float*)d_in[7];
  const float* l0_b2 = (const float*)d_in[8];
  const float* l0_ln_g = (const float*)d_in[9];
  const float* l0_ln_b = (const float*)d_in[10];
  const float* l0_res_w = (const float*)d_in[11];
  const float* l0_res_b = (const float*)d_in[12];
  const float* dec_w1 = (const float*)d_in[29];
  const float* dec_b1 = (const float*)d_in[30];
  const float* dec_w2 = (const float*)d_in[31];
  const float* dec_b2 = (const float*)d_in[32];
  const float* dec_w3 = (const float*)d_in[33];
  const float* dec_b3 = (const float*)d_in[34];

  float* h = (float*)d_ws;                       // NN*64 floats
  float* aggr = h + (size_t)NN * 64;             // NN*64 floats
  // weight-frag tables live in the aggr region (dead after last node_kernel)
  ushort* w1f = (ushort*)aggr;                   // 36*64*8 = 18432 bf16
  ushort* w2f = w1f + 18432;                     // 4*64*8  = 2048 bf16

  // ---- layer 0 ----
  hipMemsetAsync(aggr, 0, (size_t)NN * 16 * sizeof(float), stream);
  msg0_kernel<<<(NE * 16) / 256, 256, 0, stream>>>(x, ei, ea, l0_lin_w, l0_lin_b, aggr);
  node0_kernel<<<NN / 4, 256, 0, stream>>>(x, aggr, l0_w1, l0_b1, l0_w2, l0_b2,
                                           l0_ln_g, l0_ln_b, l0_res_w, l0_res_b, h);
  // ---- layers 1, 2 ----
  for (int li = 1; li <= 2; li++) {
    int base = 13 + (li - 1) * 8;
    const float* lin_w = (const float*)d_in[base + 0];
    const float* lin_b = (const float*)d_in[base + 1];
    const float* w1 = (const float*)d_in[base + 2];
    const float* b1 = (const float*)d_in[base + 3];
    const float* w2 = (const float*)d_in[base + 4];
    const float* b2 = (const float*)d_in[base + 5];
    const float* lng = (const float*)d_in[base + 6];
    const float* lnb = (const float*)d_in[base + 7];
    hipMemsetAsync(aggr, 0, (size_t)NN * 64 * sizeof(float), stream);
    msg_kernel<<<NE / 4, 256, 0, stream>>>(h, ei, ea, lin_w, lin_b, aggr);
    node_kernel<<<NN / 4, 256, 0, stream>>>(h, aggr, w1, b1, w2, b2, lng, lnb);
  }
  // ---- decoder ----
  prep_kernel<<<80, 256, 0, stream>>>(dec_w1, dec_w2, w1f, w2f);
  decoder_kernel<<<3125, 256, 0, stream>>>(h, ei, ea, w1f, w2f, dec_b1, dec_b2,
                                           dec_w3, dec_b3, (float*)d_out);
}

// Round 3
// 779.589 us; speedup vs baseline: 2.0005x; 1.3475x over previous
//
#include <hip/hip_runtime.h>

#define NN 50000
#define NE 1000000

constexpr float LN_EPS = 1e-5f;

typedef short bf16x8 __attribute__((ext_vector_type(8)));
typedef float f32x4 __attribute__((ext_vector_type(4)));

// round-to-nearest-even float -> bf16
__device__ inline ushort f2bf(float x) {
  union { float f; uint u; } v; v.f = x;
  uint r = v.u + 0x7fffu + ((v.u >> 16) & 1u);
  return (ushort)(r >> 16);
}
__device__ inline uint pkbf(float a, float b) {
  union { float f; uint u; } x, y; x.f = a; y.f = b;
  uint ra = (x.u + 0x7fffu + ((x.u >> 16) & 1u)) >> 16;
  uint rb = (y.u + 0x7fffu + ((y.u >> 16) & 1u)) & 0xffff0000u;
  return ra | rb;
}

// ---------------------------------------------------------------------------
// CSR build: histogram -> exclusive scan -> scatter (perm = edge ids by dst)
__global__ __launch_bounds__(256) void hist_kernel(const int* __restrict__ ei,
                                                   int* __restrict__ cnt) {
  int e = blockIdx.x * 256 + threadIdx.x;
  if (e < NE) atomicAdd(&cnt[ei[NE + e]], 1);
}

__global__ __launch_bounds__(256) void scan1_kernel(const int* __restrict__ cnt,
                                                    int* __restrict__ off,
                                                    int* __restrict__ bsum) {
  __shared__ int sh[256];
  int t = threadIdx.x;
  int idx = blockIdx.x * 256 + t;
  int v = (idx < NN) ? cnt[idx] : 0;
  sh[t] = v;
  __syncthreads();
  for (int o = 1; o < 256; o <<= 1) {
    int xv = (t >= o) ? sh[t - o] : 0;
    __syncthreads();
    sh[t] += xv;
    __syncthreads();
  }
  if (idx <= NN) off[idx] = sh[t] - v;      // exclusive
  if (t == 255) bsum[blockIdx.x] = sh[255];
}

__global__ __launch_bounds__(256) void scan2_kernel(int* __restrict__ bsum, int nb) {
  __shared__ int sh[256];
  int t = threadIdx.x;
  int v = (t < nb) ? bsum[t] : 0;
  sh[t] = v;
  __syncthreads();
  for (int o = 1; o < 256; o <<= 1) {
    int xv = (t >= o) ? sh[t - o] : 0;
    __syncthreads();
    sh[t] += xv;
    __syncthreads();
  }
  if (t < nb) bsum[t] = sh[t] - v;          // exclusive
}

__global__ __launch_bounds__(256) void scan3_kernel(int* __restrict__ off,
                                                    const int* __restrict__ bsum,
                                                    int* __restrict__ cnt) {
  int idx = blockIdx.x * 256 + threadIdx.x;
  if (idx <= NN) off[idx] += bsum[blockIdx.x];
  if (idx < NN) cnt[idx] = 0;               // cnt becomes the scatter cursor
}

__global__ __launch_bounds__(256) void scatter_kernel(const int* __restrict__ ei,
                                                      const int* __restrict__ off,
                                                      int* __restrict__ cur,
                                                      int* __restrict__ perm) {
  int e = blockIdx.x * 256 + threadIdx.x;
  if (e < NE) {
    int d = ei[NE + e];
    int p = off[d] + atomicAdd(&cur[d], 1);
    perm[p] = e;
  }
}

// ---------------------------------------------------------------------------
__device__ inline float lane_layernorm(float r, float g, float b) {
  float s = r;
#pragma unroll
  for (int m = 32; m >= 1; m >>= 1) s += __shfl_xor(s, m);
  float mu = s * (1.f / 64.f);
  float dv = r - mu;
  float v = dv * dv;
#pragma unroll
  for (int m = 32; m >= 1; m >>= 1) v += __shfl_xor(v, m);
  float var = v * (1.f / 64.f);
  return dv * rsqrtf(var + LN_EPS) * g + b;
}

// ---------------------------------------------------------------------------
// Fused layer 0: per-node aggregation (D=16, 4 edge slots x 16 channels) + MLP
// + residual Linear + LN. Wave per node.
__global__ __launch_bounds__(256) void layer0_fused(
    const float* __restrict__ x, float* __restrict__ hout,
    const int* __restrict__ ei, const float* __restrict__ ea,
    const int* __restrict__ perm, const int* __restrict__ off,
    const float* __restrict__ lw, const float* __restrict__ lb,
    const float* __restrict__ w1, const float* __restrict__ b1,
    const float* __restrict__ w2, const float* __restrict__ b2,
    const float* __restrict__ lng, const float* __restrict__ lnb,
    const float* __restrict__ rw, const float* __restrict__ rb) {
  int n = blockIdx.x * 4 + (threadIdx.x >> 6);
  int j = threadIdx.x & 63;
  int d = j & 15, slot = j >> 4;
  int start = off[n], end = off[n + 1];
  float lwv[8];
#pragma unroll
  for (int i = 0; i < 8; i++) lwv[i] = lw[i * 16 + d];
  float lbv = lb[d];
  float acc = 0.f;
  for (int base = start; base < end; base += 64) {
    int idx = base + j;
    int el = (idx < end) ? perm[idx] : 0;
    int sl = ei[el];
    int c = min(end - base, 64);
    for (int i0 = 0; i0 < c; i0 += 4) {
      int i = i0 + slot;
      bool valid = i < c;
      int ii = i & 63;
      int e = __shfl(el, ii);
      int s = __shfl(sl, ii);
      float ev = ea[(size_t)e * 8 + (d & 7)];
      float xs = x[(size_t)s * 16 + d];
      float m = lbv + xs;
#pragma unroll
      for (int q = 0; q < 8; q++) m = fmaf(__shfl(ev, slot * 16 + q), lwv[q], m);
      m = fmaxf(m, 0.f);
      acc += valid ? m : 0.f;
    }
  }
  // reduce partial aggregation across the 4 slots
  acc += __shfl_xor(acc, 16);
  acc += __shfl_xor(acc, 32);
  float xr = x[(size_t)n * 16 + d];          // 4x duplicated across slots
  float t = xr + acc;                        // lanes 0..15 hold t[d]
  float q1 = b1[j];
#pragma unroll 4
  for (int k = 0; k < 16; k++) q1 = fmaf(__shfl(t, k), w1[k * 64 + j], q1);
  q1 = fmaxf(q1, 0.f);
  float h2 = b2[j];
  for (int k = 0; k < 64; k++) h2 = fmaf(__shfl(q1, k), w2[k * 64 + j], h2);
  h2 = fmaxf(h2, 0.f);
  float res = rb[j];
#pragma unroll 4
  for (int k = 0; k < 16; k++) res = fmaf(__shfl(xr, k), rw[k * 64 + j], res);
  hout[(size_t)n * 64 + j] = lane_layernorm(h2 + res, lng[j], lnb[j]);
}

// ---------------------------------------------------------------------------
// Fused layers 1/2: aggregation (D=64) + MLP + identity residual + LN.
// Wave per node; edge/src ids broadcast via shfl+readfirstlane so ea loads
// are wave-uniform (scalar path) and h[src] rows are 256B coalesced.
__global__ __launch_bounds__(256) void layer_fused(
    const float* __restrict__ hin, float* __restrict__ hout,
    const int* __restrict__ ei, const float* __restrict__ ea,
    const int* __restrict__ perm, const int* __restrict__ off,
    const float* __restrict__ lw, const float* __restrict__ lb,
    const float* __restrict__ w1, const float* __restrict__ b1,
    const float* __restrict__ w2, const float* __restrict__ b2,
    const float* __restrict__ lng, const float* __restrict__ lnb) {
  int n = blockIdx.x * 4 + (threadIdx.x >> 6);
  int j = threadIdx.x & 63;
  int start = off[n], end = off[n + 1];
  float lwv[8];
#pragma unroll
  for (int i = 0; i < 8; i++) lwv[i] = lw[i * 64 + j];
  float lbv = lb[j];
  float acc = 0.f;
  for (int base = start; base < end; base += 64) {
    int idx = base + j;
    int el = (idx < end) ? perm[idx] : 0;
    int sl = ei[el];
    int c = min(end - base, 64);
    for (int i = 0; i < c; i++) {
      int e = __builtin_amdgcn_readfirstlane(__shfl(el, i));
      int s = __builtin_amdgcn_readfirstlane(__shfl(sl, i));
      const float* eap = ea + (size_t)e * 8;
      float m = lbv + hin[(size_t)s * 64 + j];
#pragma unroll
      for (int q = 0; q < 8; q++) m = fmaf(eap[q], lwv[q], m);
      acc += fmaxf(m, 0.f);
    }
  }
  float hv = hin[(size_t)n * 64 + j];
  float t = hv + acc;
  float q1 = b1[j];
  for (int k = 0; k < 64; k++) q1 = fmaf(__shfl(t, k), w1[k * 64 + j], q1);
  q1 = fmaxf(q1, 0.f);
  float h2 = b2[j];
  for (int k = 0; k < 64; k++) h2 = fmaf(__shfl(q1, k), w2[k * 64 + j], h2);
  h2 = fmaxf(h2, 0.f);
  hout[(size_t)n * 64 + j] = lane_layernorm(h2 + hv, lng[j], lnb[j]);
}

// ---------------------------------------------------------------------------
// Prep: arrange dec_w1 (264x64, K zero-padded to 288) and dec_w2 (64x32) into
// per-lane bf16 B-fragments for mfma_f32_16x16x32_bf16.
__global__ __launch_bounds__(256) void prep_kernel(
    const float* __restrict__ w1, const float* __restrict__ w2,
    ushort* __restrict__ w1f, ushort* __restrict__ w2f) {
  int t = blockIdx.x * 256 + threadIdx.x;   // grid: 80*256 = 20480 = 18432+2048
  if (t < 18432) {
    int j = t & 7, lane = (t >> 3) & 63, f = t >> 9;
    int k = (f >> 2) * 32 + ((lane >> 4) * 8) + j;
    int n = (f & 3) * 16 + (lane & 15);
    float v = (k < 264) ? w1[k * 64 + n] : 0.f;
    w1f[t] = f2bf(v);
  } else {
    int t2 = t - 18432;
    int j = t2 & 7, lane = (t2 >> 3) & 63, f = t2 >> 9;
    int k = (f >> 1) * 32 + ((lane >> 4) * 8) + j;
    int n = (f & 1) * 16 + (lane & 15);
    w2f[t2] = f2bf(w2[k * 32 + n]);
  }
}

// ---------------------------------------------------------------------------
// MFMA decoder: wave-per-16-edges (see R1 notes).
#define GPW 5
#define ZS 296
#define YS 72

__global__ __launch_bounds__(256) void decoder_kernel(
    const float* __restrict__ h, const int* __restrict__ ei,
    const float* __restrict__ ea,
    const ushort* __restrict__ w1f, const ushort* __restrict__ w2f,
    const float* __restrict__ b1, const float* __restrict__ b2,
    const float* __restrict__ w3, const float* __restrict__ b3,
    float* __restrict__ out) {
  __shared__ ushort zbuf[4][16 * ZS];
  __shared__ ushort y1buf[4][16 * YS];
  const int w = threadIdx.x >> 6, l = threadIdx.x & 63;
  const int sub = l & 15, quad = l >> 4;
  ushort* Z = zbuf[w];
  ushort* Y = y1buf[w];

#pragma unroll
  for (int t = 0; t < 3; t++) {
    int idx = l * 3 + t;
    int m = idx / 12, cp = idx % 12;
    *(uint*)&Z[m * ZS + 264 + cp * 2] = 0;
  }
  float b1v[4];
#pragma unroll
  for (int t = 0; t < 4; t++) b1v[t] = b1[t * 16 + sub];
  float b2v0 = b2[sub], b2v1 = b2[16 + sub];
  float w3v0 = w3[sub], w3v1 = w3[16 + sub];
  float b3v = b3[0];
  bf16x8 w2frag[4];
#pragma unroll
  for (int f = 0; f < 4; f++) w2frag[f] = ((const bf16x8*)w2f)[f * 64 + l];

  const int gbase = (blockIdx.x * 4 + w) * GPW;
  for (int it = 0; it < GPW; it++) {
    const int g = gbase + it;
    const int e0 = g * 16;
    int sl = ei[e0 + sub];
    int dl = ei[NE + e0 + sub];

#pragma unroll
    for (int i = 0; i < 4; i++) {
      int e = 4 * i + quad;
      int s = __shfl(sl, e), d = __shfl(dl, e);
      float4 a = ((const float4*)h)[s * 16 + sub];
      float4 b = ((const float4*)h)[d * 16 + sub];
      uint2 u;
      u.x = pkbf(a.x, a.y); u.y = pkbf(a.z, a.w);
      *(uint2*)&Z[e * ZS + sub * 4] = u;
      u.x = pkbf(b.x, b.y); u.y = pkbf(b.z, b.w);
      *(uint2*)&Z[e * ZS + 64 + sub * 4] = u;
      u.x = pkbf(fabsf(a.x - b.x), fabsf(a.y - b.y));
      u.y = pkbf(fabsf(a.z - b.z), fabsf(a.w - b.w));
      *(uint2*)&Z[e * ZS + 128 + sub * 4] = u;
      u.x = pkbf(a.x * b.x, a.y * b.y);
      u.y = pkbf(a.z * b.z, a.w * b.w);
      *(uint2*)&Z[e * ZS + 192 + sub * 4] = u;
    }
    {
      float2 eav = ((const float2*)ea)[e0 * 4 + l];
      *(uint*)&Z[(l >> 2) * ZS + 256 + 2 * (l & 3)] = pkbf(eav.x, eav.y);
    }

    f32x4 acc[4];
#pragma unroll
    for (int t = 0; t < 4; t++) acc[t] = (f32x4){0.f, 0.f, 0.f, 0.f};
    for (int s = 0; s < 9; s++) {
      bf16x8 af = *(const bf16x8*)&Z[sub * ZS + s * 32 + quad * 8];
#pragma unroll
      for (int t = 0; t < 4; t++)
        acc[t] = __builtin_amdgcn_mfma_f32_16x16x32_bf16(
            af, ((const bf16x8*)w1f)[(s * 4 + t) * 64 + l], acc[t], 0, 0, 0);
    }
#pragma unroll
    for (int t = 0; t < 4; t++)
#pragma unroll
      for (int r = 0; r < 4; r++)
        Y[(quad * 4 + r) * YS + t * 16 + sub] = f2bf(fmaxf(acc[t][r] + b1v[t], 0.f));

    f32x4 acc2[2];
    acc2[0] = (f32x4){0.f, 0.f, 0.f, 0.f};
    acc2[1] = (f32x4){0.f, 0.f, 0.f, 0.f};
#pragma unroll
    for (int ks = 0; ks < 2; ks++) {
      union { bf16x8 v; ushort4 u[2]; } ya;
      int o = sub * YS + ks * 32 + quad * 8;
      ya.u[0] = *(const ushort4*)&Y[o];
      ya.u[1] = *(const ushort4*)&Y[o + 4];
      acc2[0] = __builtin_amdgcn_mfma_f32_16x16x32_bf16(ya.v, w2frag[ks * 2 + 0], acc2[0], 0, 0, 0);
      acc2[1] = __builtin_amdgcn_mfma_f32_16x16x32_bf16(ya.v, w2frag[ks * 2 + 1], acc2[1], 0, 0, 0);
    }
#pragma unroll
    for (int r = 0; r < 4; r++) {
      float o = fmaxf(acc2[0][r] + b2v0, 0.f) * w3v0 +
                fmaxf(acc2[1][r] + b2v1, 0.f) * w3v1;
      o += __shfl_xor(o, 1);
      o += __shfl_xor(o, 2);
      o += __shfl_xor(o, 4);
      o += __shfl_xor(o, 8);
      if (sub == 0) out[e0 + quad * 4 + r] = o + b3v;
    }
  }
}

// ---------------------------------------------------------------------------
extern "C" void kernel_launch(void* const* d_in, const int* in_sizes, int n_in,
                              void* d_out, int out_size, void* d_ws, size_t ws_size,
                              hipStream_t stream) {
  const float* x = (const float*)d_in[0];
  const int* ei = (const int*)d_in[1];
  const float* ea = (const float*)d_in[2];
  const float* l0_lin_w = (const float*)d_in[3];
  const float* l0_lin_b = (const float*)d_in[4];
  const float* l0_w1 = (const float*)d_in[5];
  const float* l0_b1 = (const float*)d_in[6];
  const float* l0_w2 = (const float*)d_in[7];
  const float* l0_b2 = (const float*)d_in[8];
  const float* l0_ln_g = (const float*)d_in[9];
  const float* l0_ln_b = (const float*)d_in[10];
  const float* l0_res_w = (const float*)d_in[11];
  const float* l0_res_b = (const float*)d_in[12];
  const float* dec_w1 = (const float*)d_in[29];
  const float* dec_b1 = (const float*)d_in[30];
  const float* dec_w2 = (const float*)d_in[31];
  const float* dec_b2 = (const float*)d_in[32];
  const float* dec_w3 = (const float*)d_in[33];
  const float* dec_b3 = (const float*)d_in[34];

  float* h_a = (float*)d_ws;                      // NN*64 f32
  float* h_b = h_a + (size_t)NN * 64;             // NN*64 f32
  int* perm = (int*)(h_b + (size_t)NN * 64);      // NE
  int* off = perm + NE;                           // NN+1
  int* cnt = off + (NN + 1);                      // NN (also scatter cursor)
  int* bsum = cnt + NN;                           // 256
  ushort* w1f = (ushort*)(bsum + 256);            // 18432 bf16
  ushort* w2f = w1f + 18432;                      // 2048 bf16

  const int EB = (NE + 255) / 256;                // 3907
  const int SB = (NN + 256) / 256;                // 196 (covers idx 0..NN)

  // ---- CSR build ----
  hipMemsetAsync(cnt, 0, (size_t)NN * sizeof(int), stream);
  hist_kernel<<<EB, 256, 0, stream>>>(ei, cnt);
  scan1_kernel<<<SB, 256, 0, stream>>>(cnt, off, bsum);
  scan2_kernel<<<1, 256, 0, stream>>>(bsum, SB);
  scan3_kernel<<<SB, 256, 0, stream>>>(off, bsum, cnt);
  scatter_kernel<<<EB, 256, 0, stream>>>(ei, off, cnt, perm);

  // ---- fused GNN layers ----
  layer0_fused<<<NN / 4, 256, 0, stream>>>(x, h_a, ei, ea, perm, off,
                                           l0_lin_w, l0_lin_b, l0_w1, l0_b1,
                                           l0_w2, l0_b2, l0_ln_g, l0_ln_b,
                                           l0_res_w, l0_res_b);
  layer_fused<<<NN / 4, 256, 0, stream>>>(h_a, h_b, ei, ea, perm, off,
                                          (const float*)d_in[13], (const float*)d_in[14],
                                          (const float*)d_in[15], (const float*)d_in[16],
                                          (const float*)d_in[17], (const float*)d_in[18],
                                          (const float*)d_in[19], (const float*)d_in[20]);
  layer_fused<<<NN / 4, 256, 0, stream>>>(h_b, h_a, ei, ea, perm, off,
                                          (const float*)d_in[21], (const float*)d_in[22],
                                          (const float*)d_in[23], (const float*)d_in[24],
                                          (const float*)d_in[25], (const float*)d_in[26],
                                          (const float*)d_in[27], (const float*)d_in[28]);

  // ---- decoder ----
  prep_kernel<<<80, 256, 0, stream>>>(dec_w1, dec_w2, w1f, w2f);
  decoder_kernel<<<3125, 256, 0, stream>>>(h_a, ei, ea, w1f, w2f, dec_b1, dec_b2,
                                           dec_w3, dec_b3, (float*)d_out);
}